// Round 5
// baseline (220.943 us; speedup 1.0000x reference)
//
#include <hip/hip_runtime.h>
#include <math.h>

#define D_MODEL 256
#define NHEAD 4
#define HEAD_DIM 64
#define SEQ 4096
#define BATCH 4
#define MROWS (BATCH * SEQ)

typedef __attribute__((ext_vector_type(8))) short short8;
typedef __attribute__((ext_vector_type(4))) short short4v;
typedef __attribute__((ext_vector_type(8))) __bf16 bf16x8;
typedef __attribute__((ext_vector_type(4))) float f32x4;

__device__ inline short f2bf(float f) {  // RNE fp32->bf16
  unsigned u = __float_as_uint(f);
  u += 0x7fffu + ((u >> 16) & 1u);
  return (short)(u >> 16);
}
__device__ inline bf16x8 as_bf8(short8 s) {
  union { short8 s; bf16x8 b; } u;
  u.s = s;
  return u.b;
}
// async global->LDS, 16B per lane; LDS dest = wave-uniform base + lane*16
__device__ __forceinline__ void g2lds16(const void* g, void* l) {
  __builtin_amdgcn_global_load_lds(
      (const __attribute__((address_space(1))) unsigned int*)g,
      (__attribute__((address_space(3))) unsigned int*)l, 16, 0, 0);
}

// ---------------- one-shot weight fp32->bf16 convert (5 x 256x256) --------
__global__ __launch_bounds__(256) void wcvt(const float* __restrict__ s0, const float* __restrict__ s1,
                                            const float* __restrict__ s2, const float* __restrict__ s3,
                                            const float* __restrict__ s4, short* __restrict__ d0,
                                            short* __restrict__ d1, short* __restrict__ d2,
                                            short* __restrict__ d3, short* __restrict__ d4) {
  int mat = blockIdx.x >> 6;
  int idx = ((blockIdx.x & 63) * 256 + threadIdx.x) * 4;
  const float* s = mat == 0 ? s0 : mat == 1 ? s1 : mat == 2 ? s2 : mat == 3 ? s3 : s4;
  short* d = mat == 0 ? d0 : mat == 1 ? d1 : mat == 2 ? d2 : mat == 3 ? d3 : d4;
  float4 f = *(const float4*)(s + idx);
  short4v o = {f2bf(f.x), f2bf(f.y), f2bf(f.z), f2bf(f.w)};
  *(short4v*)(d + idx) = o;
}

// ---------------- LayerNorm fp32 -> bf16, one wave per row -----------------
__global__ __launch_bounds__(256) void ln_bf(const float* __restrict__ x,
                                             const float* __restrict__ g,
                                             const float* __restrict__ b,
                                             short* __restrict__ o) {
  int lane = threadIdx.x & 63;
  int row = (blockIdx.x << 2) + (threadIdx.x >> 6);
  float4 v = ((const float4*)(x + (size_t)row * D_MODEL))[lane];
  float s = v.x + v.y + v.z + v.w;
#pragma unroll
  for (int off = 32; off > 0; off >>= 1) s += __shfl_xor(s, off);
  float mu = s * (1.0f / D_MODEL);
  float d0 = v.x - mu, d1 = v.y - mu, d2 = v.z - mu, d3 = v.w - mu;
  float ss = d0 * d0 + d1 * d1 + d2 * d2 + d3 * d3;
#pragma unroll
  for (int off = 32; off > 0; off >>= 1) ss += __shfl_xor(ss, off);
  float r = rsqrtf(ss * (1.0f / D_MODEL) + 1e-5f);
  float4 gv = ((const float4*)g)[lane];
  float4 bv = ((const float4*)b)[lane];
  short4v out = {f2bf(d0 * r * gv.x + bv.x), f2bf(d1 * r * gv.y + bv.y),
                 f2bf(d2 * r * gv.z + bv.z), f2bf(d3 * r * gv.w + bv.w)};
  *(short4v*)(o + (size_t)row * D_MODEL + lane * 4) = out;
}

#define QSCALE 0.1803368801111204f  /* 0.125 * log2(e): exp2-domain scores */

// ---------------- fused QKV GEMM: 128x128 tile, 4 waves of 64x64 -----------
// grid (128, 6): y>>1 selects Q/K/V, (y&1)*128 = n0. K and VT written in
// pre-swizzled attention chunk-image order.
__global__ __launch_bounds__(256) void qkv_fused(const short* __restrict__ Wqb,
                                                 const short* __restrict__ Wkb,
                                                 const short* __restrict__ Wvb,
                                                 const short* __restrict__ Xb,
                                                 short* __restrict__ qo,
                                                 short* __restrict__ kimg,
                                                 short* __restrict__ vimg) {
  __shared__ __align__(16) short Xs[128 * 32];
  __shared__ __align__(16) short Ws[128 * 32];
  const int t = threadIdx.x, lane = t & 63;
  const int l15 = lane & 15, quad = lane >> 4;
  const int wv = t >> 6, wm = wv & 1, wn = wv >> 1;
  const int m0 = blockIdx.x * 128;
  const int which = blockIdx.y >> 1;
  const int n0 = (blockIdx.y & 1) * 128;
  const short* Wb = which == 0 ? Wqb : which == 1 ? Wkb : Wvb;
  const int srow = t >> 2, scol = (t & 3) * 8;
  const int sbase = __builtin_amdgcn_readfirstlane((t >> 6) * 512);

  f32x4 acc[4][4];
#pragma unroll
  for (int i = 0; i < 4; i++)
#pragma unroll
    for (int j = 0; j < 4; j++) acc[i][j] = (f32x4){0.f, 0.f, 0.f, 0.f};

  for (int ks = 0; ks < 8; ks++) {
    const int k0 = ks * 32;
#pragma unroll
    for (int i = 0; i < 2; i++) {
      g2lds16(Xb + (size_t)(m0 + i * 64 + srow) * D_MODEL + k0 + scol, &Xs[i * 2048 + sbase]);
      g2lds16(Wb + (size_t)(n0 + i * 64 + srow) * D_MODEL + k0 + scol, &Ws[i * 2048 + sbase]);
    }
    __syncthreads();
    bf16x8 fx[4], fw[4];
#pragma unroll
    for (int i = 0; i < 4; i++) {
      fx[i] = as_bf8(*(short8*)&Xs[(wm * 64 + i * 16 + l15) * 32 + quad * 8]);
      fw[i] = as_bf8(*(short8*)&Ws[(wn * 64 + i * 16 + l15) * 32 + quad * 8]);
    }
    if (which == 2) {
#pragma unroll
      for (int mt = 0; mt < 4; mt++)
#pragma unroll
        for (int nt = 0; nt < 4; nt++)
          acc[mt][nt] = __builtin_amdgcn_mfma_f32_16x16x32_bf16(fx[mt], fw[nt], acc[mt][nt], 0, 0, 0);
    } else {
#pragma unroll
      for (int mt = 0; mt < 4; mt++)
#pragma unroll
        for (int nt = 0; nt < 4; nt++)
          acc[mt][nt] = __builtin_amdgcn_mfma_f32_16x16x32_bf16(fw[nt], fx[mt], acc[mt][nt], 0, 0, 0);
    }
    __syncthreads();
  }

#pragma unroll
  for (int mt = 0; mt < 4; mt++)
#pragma unroll
    for (int nt = 0; nt < 4; nt++) {
      f32x4 v = acc[mt][nt];
      if (which == 2) {  // VT image: D[m=s][n=feature]
        int n = n0 + wn * 64 + nt * 16 + l15;
        int mr = m0 + wm * 64 + mt * 16 + quad * 4;
        int b = mr >> 12, s = mr & 4095, h = n >> 6, d = n & 63;
        size_t off = ((size_t)(b * NHEAD + h) * 64 + (s >> 6)) * 4096 +
                     (size_t)d * 64 + ((((s & 63) >> 3) ^ (d & 7)) * 8) + (s & 7);
        short4v o = {f2bf(v[0]), f2bf(v[1]), f2bf(v[2]), f2bf(v[3])};
        *(short4v*)(vimg + off) = o;
      } else {
        int m = m0 + wm * 64 + mt * 16 + l15;
        int nb = n0 + wn * 64 + nt * 16 + quad * 4;
        if (which == 0) {  // Q row-major, exp2-domain scale folded in
          v *= QSCALE;
          short4v o = {f2bf(v[0]), f2bf(v[1]), f2bf(v[2]), f2bf(v[3])};
          *(short4v*)(qo + (size_t)m * D_MODEL + nb) = o;
        } else {  // K image
          int b = m >> 12, s = m & 4095, h = nb >> 6, d = nb & 63;
          size_t off = ((size_t)(b * NHEAD + h) * 64 + (s >> 6)) * 4096 +
                       (size_t)(s & 63) * 64 + (((d >> 3) ^ (s & 7)) * 8) + (d & 7);
          short4v o = {f2bf(v[0]), f2bf(v[1]), f2bf(v[2]), f2bf(v[3])};
          *(short4v*)(kimg + off) = o;
        }
      }
    }
}

// ---------------- fused FFN: out = relu(h@W1^T+b1)@W2^T + b2 + xt ----------
// Block = 64 rows. f1 never touches HBM: GEMM1 accumulators (D[n1][m],
// col=lane&15=m) are packed into F1s[m][n1] (stride 264) so GEMM2 reads them
// as contiguous b128 A-fragments. W1/W2 share one 16 KB staging buffer.
__global__ __launch_bounds__(256) void ffn_fused(const short* __restrict__ W1b,
                                                 const short* __restrict__ W2b,
                                                 const short* __restrict__ Hb,
                                                 const float* __restrict__ bf1,
                                                 const float* __restrict__ bf2,
                                                 const float* __restrict__ xt,
                                                 float* __restrict__ out) {
  __shared__ __align__(16) short Hs[64 * 32];     // 4 KB
  __shared__ __align__(16) short Ws[256 * 32];    // 16 KB
  __shared__ __align__(16) short F1s[64 * 264];   // ~33 KB, 16B-aligned rows
  const int t = threadIdx.x, lane = t & 63;
  const int l15 = lane & 15, quad = lane >> 4;
  const int wv = t >> 6, wm = wv & 1, wn = wv >> 1;
  const int m0 = blockIdx.x * 64;
  const int srow = t >> 2, scol = (t & 3) * 8;
  const int sbase = __builtin_amdgcn_readfirstlane((t >> 6) * 512);

  // ---- GEMM1: D1[n1][m] = W1 . h^T (wave: 32m x 128n1) ----
  f32x4 acc[2][8];
#pragma unroll
  for (int i = 0; i < 2; i++)
#pragma unroll
    for (int j = 0; j < 8; j++) acc[i][j] = (f32x4){0.f, 0.f, 0.f, 0.f};

  for (int ks = 0; ks < 8; ks++) {
    const int k0 = ks * 32;
    g2lds16(Hb + (size_t)(m0 + srow) * D_MODEL + k0 + scol, &Hs[sbase]);
#pragma unroll
    for (int i = 0; i < 4; i++)
      g2lds16(W1b + (size_t)(i * 64 + srow) * D_MODEL + k0 + scol, &Ws[i * 2048 + sbase]);
    __syncthreads();
    bf16x8 fx[2], fw[8];
#pragma unroll
    for (int i = 0; i < 2; i++)
      fx[i] = as_bf8(*(short8*)&Hs[(wm * 32 + i * 16 + l15) * 32 + quad * 8]);
#pragma unroll
    for (int i = 0; i < 8; i++)
      fw[i] = as_bf8(*(short8*)&Ws[(wn * 128 + i * 16 + l15) * 32 + quad * 8]);
#pragma unroll
    for (int mt = 0; mt < 2; mt++)
#pragma unroll
      for (int nt = 0; nt < 8; nt++)
        acc[mt][nt] = __builtin_amdgcn_mfma_f32_16x16x32_bf16(fw[nt], fx[mt], acc[mt][nt], 0, 0, 0);
    __syncthreads();
  }

  // ---- epilogue 1: bias + relu -> F1s[m][n1] (b64 packed writes) ----
#pragma unroll
  for (int mt = 0; mt < 2; mt++)
#pragma unroll
    for (int nt = 0; nt < 8; nt++) {
      int n1 = wn * 128 + nt * 16 + quad * 4;
      int ml = wm * 32 + mt * 16 + l15;
      float4 bv = *(const float4*)(bf1 + n1);
      f32x4 v = acc[mt][nt];
      short4v o = {f2bf(fmaxf(v[0] + bv.x, 0.f)), f2bf(fmaxf(v[1] + bv.y, 0.f)),
                   f2bf(fmaxf(v[2] + bv.z, 0.f)), f2bf(fmaxf(v[3] + bv.w, 0.f))};
      *(short4v*)&F1s[ml * 264 + n1] = o;
    }
  __syncthreads();

  // ---- GEMM2: D2[m][n2] = f1 . W2^T (wave: 32m x 128n2) ----
  f32x4 a2[2][8];
#pragma unroll
  for (int i = 0; i < 2; i++)
#pragma unroll
    for (int j = 0; j < 8; j++) a2[i][j] = (f32x4){0.f, 0.f, 0.f, 0.f};

  for (int ks = 0; ks < 8; ks++) {
    const int k0 = ks * 32;
#pragma unroll
    for (int i = 0; i < 4; i++)
      g2lds16(W2b + (size_t)(i * 64 + srow) * D_MODEL + k0 + scol, &Ws[i * 2048 + sbase]);
    __syncthreads();
    bf16x8 ff[2], f2[8];
#pragma unroll
    for (int i = 0; i < 2; i++)
      ff[i] = as_bf8(*(short8*)&F1s[(wm * 32 + i * 16 + l15) * 264 + k0 + quad * 8]);
#pragma unroll
    for (int i = 0; i < 8; i++)
      f2[i] = as_bf8(*(short8*)&Ws[(wn * 128 + i * 16 + l15) * 32 + quad * 8]);
#pragma unroll
    for (int mt = 0; mt < 2; mt++)
#pragma unroll
      for (int nt = 0; nt < 8; nt++)
        a2[mt][nt] = __builtin_amdgcn_mfma_f32_16x16x32_bf16(ff[mt], f2[nt], a2[mt][nt], 0, 0, 0);
    __syncthreads();
  }

  // ---- epilogue 2: + b2 + xt -> out (fp32) ----
#pragma unroll
  for (int mt = 0; mt < 2; mt++)
#pragma unroll
    for (int nt = 0; nt < 8; nt++) {
      int n2 = wn * 128 + nt * 16 + l15;
      int m = m0 + wm * 32 + mt * 16 + quad * 4;
      float b2v = bf2[n2];
      f32x4 v = a2[mt][nt];
#pragma unroll
      for (int r = 0; r < 4; r++) {
        size_t a = (size_t)(m + r) * D_MODEL + n2;
        out[a] = v[r] + b2v + xt[a];
      }
    }
}

// ---------------- MFMA flash attention v3 (unchanged) ----------------------
__global__ __launch_bounds__(256) void attn_v3(const short* __restrict__ qb,
                                               const short* __restrict__ kimg,
                                               const short* __restrict__ vimg,
                                               const float* __restrict__ x,
                                               float* __restrict__ xt) {
  __shared__ __align__(16) short Ks[2 * 4096];
  __shared__ __align__(16) short Vs[2 * 4096];
  __shared__ __align__(16) short Pt[4][16 * 136];  // per-wave [q][key], padded

  const int t = threadIdx.x, lane = t & 63, w = t >> 6;
  const int quad = lane >> 4, l15 = lane & 15;
  const int pair = blockIdx.x;
  const int bh = blockIdx.y, b = bh >> 2, h = bh & 3;
  const int ldsoff = __builtin_amdgcn_readfirstlane(w * 512);
  const short* kb_bh = kimg + (size_t)bh * 64 * 4096;
  const short* vb_bh = vimg + (size_t)bh * 64 * 4096;

  for (int tile = 0; tile < 2; tile++) {
    const int qt = tile == 0 ? 63 - pair : pair;
    const int q0 = qt * 64;
    const int qrow = q0 + w * 16 + l15;
    const int wq_lo = q0 + w * 16, wq_hi = wq_lo + 15;

    bf16x8 qf0, qf1;
    {
      const short* qp = qb + ((size_t)(b * SEQ + qrow)) * D_MODEL + h * HEAD_DIM + quad * 8;
      qf0 = as_bf8(*(const short8*)qp);
      qf1 = as_bf8(*(const short8*)(qp + 32));
    }
    f32x4 oacc[4];
#pragma unroll
    for (int i = 0; i < 4; i++) oacc[i] = (f32x4){0.f, 0.f, 0.f, 0.f};
    float mrun = -1e30f, lrun = 0.f;

    const int niter = (qt + 2) >> 1;
    for (int it = 0; it < niter; it++) {
      const int j0 = it * 128;
      const short* kc_base = kb_bh + (size_t)(2 * it) * 4096;
      const short* vc_base = vb_bh + (size_t)(2 * it) * 4096;
#pragma unroll
      for (int i = 0; i < 4; i++) {
        g2lds16(kc_base + i * 2048 + t * 8, &Ks[i * 2048 + ldsoff]);
        g2lds16(vc_base + i * 2048 + t * 8, &Vs[i * 2048 + ldsoff]);
      }
      __syncthreads();

      const bool half1 = (j0 + 64) <= wq_hi;  // wave-uniform
      const int kcmax = half1 ? 8 : 4;
      f32x4 st[8];
#pragma unroll
      for (int kc = 0; kc < 8; kc++) {
        if (kc < kcmax) {
          int key = kc * 16 + l15;
          int img = (key >> 6) * 4096, r = key & 63;
          f32x4 z = (f32x4){0.f, 0.f, 0.f, 0.f};
          bf16x8 kf0 = as_bf8(*(short8*)&Ks[img + r * 64 + ((quad ^ (r & 7)) * 8)]);
          bf16x8 kf1 = as_bf8(*(short8*)&Ks[img + r * 64 + (((4 + quad) ^ (r & 7)) * 8)]);
          z = __builtin_amdgcn_mfma_f32_16x16x32_bf16(kf0, qf0, z, 0, 0, 0);
          z = __builtin_amdgcn_mfma_f32_16x16x32_bf16(kf1, qf1, z, 0, 0, 0);
          st[kc] = z;
        } else {
          st[kc] = (f32x4){-1e30f, -1e30f, -1e30f, -1e30f};
        }
      }
      if (j0 + 127 > wq_lo) {
#pragma unroll
        for (int kc = 0; kc < 8; kc++)
#pragma unroll
          for (int r = 0; r < 4; r++)
            if (j0 + kc * 16 + quad * 4 + r > qrow) st[kc][r] = -1e30f;
      }
      float smax = -1e30f;
#pragma unroll
      for (int kc = 0; kc < 8; kc++)
#pragma unroll
        for (int r = 0; r < 4; r++) smax = fmaxf(smax, st[kc][r]);
      smax = fmaxf(smax, __shfl_xor(smax, 16));
      smax = fmaxf(smax, __shfl_xor(smax, 32));
      float mn = fmaxf(mrun, smax);
      float alpha = __builtin_amdgcn_exp2f(mrun - mn);
      mrun = mn;
      float psum = 0.f;
#pragma unroll
      for (int kc = 0; kc < 8; kc++) {
        if (kc < kcmax) {
#pragma unroll
          for (int r = 0; r < 4; r++) {
            float p = __builtin_amdgcn_exp2f(st[kc][r] - mn);
            st[kc][r] = p;
            psum += p;
          }
        }
      }
      psum += __shfl_xor(psum, 16);
      psum += __shfl_xor(psum, 32);
      lrun = lrun * alpha + psum;
#pragma unroll
      for (int i = 0; i < 4; i++) oacc[i] *= alpha;
#pragma unroll
      for (int kc = 0; kc < 8; kc++) {
        if (kc < kcmax) {
          unsigned u0 = (__float_as_uint(st[kc][0]) >> 16) | (__float_as_uint(st[kc][1]) & 0xffff0000u);
          unsigned u1 = (__float_as_uint(st[kc][2]) >> 16) | (__float_as_uint(st[kc][3]) & 0xffff0000u);
          uint2 uu = {u0, u1};
          *(uint2*)&Pt[w][l15 * 136 + kc * 16 + quad * 4] = uu;
        }
      }
      const int fimax = half1 ? 4 : 2;
      bf16x8 pf[4];
#pragma unroll
      for (int fi = 0; fi < 4; fi++)
        if (fi < fimax) pf[fi] = as_bf8(*(short8*)&Pt[w][l15 * 136 + fi * 32 + quad * 8]);
#pragma unroll
      for (int dt = 0; dt < 4; dt++) {
        f32x4 o = oacc[dt];
        int d = dt * 16 + l15;
#pragma unroll
        for (int fi = 0; fi < 4; fi++) {
          if (fi < fimax) {
            bf16x8 vf = as_bf8(*(short8*)&Vs[(fi >> 1) * 4096 + d * 64 +
                                             ((((fi & 1) * 4 + quad) ^ (d & 7)) * 8)]);
            o = __builtin_amdgcn_mfma_f32_16x16x32_bf16(vf, pf[fi], o, 0, 0, 0);
          }
        }
        oacc[dt] = o;
      }
      __syncthreads();
    }

    float inv = 1.0f / lrun;
    size_t rowb = ((size_t)(b * SEQ + qrow)) * D_MODEL + h * HEAD_DIM;
#pragma unroll
    for (int dt = 0; dt < 4; dt++) {
      size_t a = rowb + dt * 16 + quad * 4;
      float4 xv = *(const float4*)(x + a);
      float4 o = make_float4(oacc[dt][0] * inv + xv.x, oacc[dt][1] * inv + xv.y,
                             oacc[dt][2] * inv + xv.z, oacc[dt][3] * inv + xv.w);
      *(float4*)(xt + a) = o;
    }
  }
}

// ---------------------------------------------------------------------------
extern "C" void kernel_launch(void* const* d_in, const int* in_sizes, int n_in,
                              void* d_out, int out_size, void* d_ws,
                              size_t ws_size, hipStream_t stream) {
  const float* x = (const float*)d_in[0];
  const float* Wq = (const float*)d_in[1];
  const float* Wk = (const float*)d_in[2];
  const float* Wv = (const float*)d_in[3];
  const float* g1 = (const float*)d_in[4];
  const float* b1 = (const float*)d_in[5];
  const float* g2 = (const float*)d_in[6];
  const float* b2 = (const float*)d_in[7];
  const float* W1 = (const float*)d_in[8];
  const float* bf1 = (const float*)d_in[9];
  const float* W2 = (const float*)d_in[10];
  const float* bf2 = (const float*)d_in[11];
  float* out = (float*)d_out;

  char* ws = (char*)d_ws;
  float* xt = (float*)ws;                      // 16 MB
  short* q_bf = (short*)(ws + (16u << 20));    // 8 MB
  short* kimg = (short*)(ws + (24u << 20));    // 8 MB (swizzled chunk images)
  short* vimg = (short*)(ws + (32u << 20));    // 8 MB (swizzled chunk images)
  short* xn_bf = (short*)(ws + (40u << 20));   // 8 MB (xn, then h)
  short* wq_bf = (short*)(ws + (48u << 20));
  short* wk_bf = wq_bf + 65536;
  short* wv_bf = wq_bf + 2 * 65536;
  short* w1_bf = wq_bf + 3 * 65536;
  short* w2_bf = wq_bf + 4 * 65536;

  dim3 blk(256);
  wcvt<<<320, blk, 0, stream>>>(Wq, Wk, Wv, W1, W2, wq_bf, wk_bf, wv_bf, w1_bf, w2_bf);
  ln_bf<<<MROWS / 4, blk, 0, stream>>>(x, g1, b1, xn_bf);
  qkv_fused<<<dim3(MROWS / 128, 6), blk, 0, stream>>>(wq_bf, wk_bf, wv_bf, xn_bf,
                                                      q_bf, kimg, vimg);
  attn_v3<<<dim3(32, 16), blk, 0, stream>>>(q_bf, kimg, vimg, x, xt);
  ln_bf<<<MROWS / 4, blk, 0, stream>>>(xt, g2, b2, xn_bf);
  ffn_fused<<<MROWS / 64, blk, 0, stream>>>(w1_bf, w2_bf, xn_bf, bf1, bf2, xt, out);
}